// Round 19
// baseline (317.060 us; speedup 1.0000x reference)
//
#include <hip/hip_runtime.h>
#include <math.h>

#define NN 8192
#define DD 256
#define TOPK 64
#define CAP 96            // survivor capacity per row
#define CCAP 256          // candidate capacity for exact select
#define CRMAX 2048        // score-chunk rows: Sc = 64 MB -> L3-resident
#define NEGVAL (-1000000000.0f)

typedef _Float16 f16;
typedef f16  f16x4 __attribute__((ext_vector_type(4)));
typedef f16  f16x8 __attribute__((ext_vector_type(8)));
typedef float f32x4 __attribute__((ext_vector_type(4)));

// ---------------------------------------------------------------------------
// Fused QKV projection (R11/R13, proven 55us): shared-X 64x64x3 tiles, BK=32,
// padded LDS rows (stride 68). Per-output fmaf chain is k-ascending ->
// bitwise-identical Q/K/V (selection boundary demands exactness).
// Q,K written directly as f16 hi/lo score layout; V as f32.
// ---------------------------------------------------------------------------
__global__ __launch_bounds__(256)
void gemm_qkv(const float* __restrict__ X,
              const float* __restrict__ Wq, const float* __restrict__ bq,
              const float* __restrict__ Wk, const float* __restrict__ bk,
              const float* __restrict__ Wv, const float* __restrict__ bv,
              f16* __restrict__ Qs, f16* __restrict__ Ks,
              float* __restrict__ Vf)
{
  __shared__ float As[32][68];
  __shared__ float Bs[3][32][68];
  const int t  = threadIdx.x;
  const int tm = t & 15;
  const int tn = t >> 4;
  const int m0 = blockIdx.x * 64;
  const int n0 = blockIdx.y * 64;

  float acc[3][4][4];
#pragma unroll
  for (int g = 0; g < 3; ++g)
#pragma unroll
    for (int i = 0; i < 4; ++i)
#pragma unroll
      for (int j = 0; j < 4; ++j) acc[g][i][j] = 0.0f;

  for (int k0 = 0; k0 < DD; k0 += 32) {
    __syncthreads();
#pragma unroll
    for (int i = 0; i < 2; ++i) {
      const int slot = t + i * 256;
      const int row  = slot >> 3;
      const int c4   = (slot & 7) << 2;
      float4 av = *(const float4*)(X + (size_t)(m0 + row) * DD + k0 + c4);
      As[c4 + 0][row] = av.x; As[c4 + 1][row] = av.y;
      As[c4 + 2][row] = av.z; As[c4 + 3][row] = av.w;
      float4 q4 = *(const float4*)(Wq + (size_t)(n0 + row) * DD + k0 + c4);
      Bs[0][c4 + 0][row] = q4.x; Bs[0][c4 + 1][row] = q4.y;
      Bs[0][c4 + 2][row] = q4.z; Bs[0][c4 + 3][row] = q4.w;
      float4 k4 = *(const float4*)(Wk + (size_t)(n0 + row) * DD + k0 + c4);
      Bs[1][c4 + 0][row] = k4.x; Bs[1][c4 + 1][row] = k4.y;
      Bs[1][c4 + 2][row] = k4.z; Bs[1][c4 + 3][row] = k4.w;
      float4 v4 = *(const float4*)(Wv + (size_t)(n0 + row) * DD + k0 + c4);
      Bs[2][c4 + 0][row] = v4.x; Bs[2][c4 + 1][row] = v4.y;
      Bs[2][c4 + 2][row] = v4.z; Bs[2][c4 + 3][row] = v4.w;
    }
    __syncthreads();
#pragma unroll
    for (int kk = 0; kk < 32; ++kk) {
      float a[4];
      *(float4*)&a[0] = *(const float4*)&As[kk][tm * 4];
      float b0[4], b1[4], b2[4];
      *(float4*)&b0[0] = *(const float4*)&Bs[0][kk][tn * 4];
      *(float4*)&b1[0] = *(const float4*)&Bs[1][kk][tn * 4];
      *(float4*)&b2[0] = *(const float4*)&Bs[2][kk][tn * 4];
#pragma unroll
      for (int i = 0; i < 4; ++i)
#pragma unroll
        for (int j = 0; j < 4; ++j) {
          acc[0][i][j] = fmaf(a[i], b0[j], acc[0][i][j]);
          acc[1][i][j] = fmaf(a[i], b1[j], acc[1][i][j]);
          acc[2][i][j] = fmaf(a[i], b2[j], acc[2][i][j]);
        }
    }
  }

#pragma unroll
  for (int r = 0; r < 4; ++r) {
    const int grow  = m0 + tm * 4 + r;
    const int gcol0 = n0 + tn * 4;
    {
      f16x4 h4, l4;
#pragma unroll
      for (int c = 0; c < 4; ++c) {
        const float val = acc[0][r][c] + bq[gcol0 + c];
        f16 h = (f16)val;
        h4[c] = h;
        l4[c] = (f16)(val - (float)h);
      }
      f16* base = Qs + (size_t)grow * 768 + gcol0;
      *(f16x4*)(base)       = h4;
      *(f16x4*)(base + 256) = h4;
      *(f16x4*)(base + 512) = l4;
    }
    {
      f16x4 h4, l4;
#pragma unroll
      for (int c = 0; c < 4; ++c) {
        const float val = acc[1][r][c] + bk[gcol0 + c];
        f16 h = (f16)val;
        h4[c] = h;
        l4[c] = (f16)(val - (float)h);
      }
      f16* base = Ks + (size_t)grow * 768 + gcol0;
      *(f16x4*)(base)       = h4;
      *(f16x4*)(base + 256) = l4;
      *(f16x4*)(base + 512) = h4;
    }
    {
      float val[4];
#pragma unroll
      for (int c = 0; c < 4; ++c)
        val[c] = acc[2][r][c] + bv[gcol0 + c];
      *(float4*)(Vf + (size_t)grow * DD + gcol0) =
          make_float4(val[0], val[1], val[2], val[3]);
    }
  }
}

// ---------------------------------------------------------------------------
typedef __attribute__((address_space(1))) const void GV;
typedef __attribute__((address_space(3))) void LV;
__device__ __forceinline__ void gl_lds16(const void* g, void* l) {
  __builtin_amdgcn_global_load_lds((GV*)g, (LV*)l, 16, 0, 0);
}

// ---------------------------------------------------------------------------
// MFMA scores GEMM v4b (R18, proven): 256x256 tile, BK=64, 8 waves, 2 LDS
// dbufs, counted-vmcnt depth-1 pipeline, both-sides swizzle; grid axes
// swapped (x = column block) for per-XCD L2 locality of the K panels.
// ---------------------------------------------------------------------------
__global__ __launch_bounds__(512, 1)
void gemm_scores_f16(const f16* __restrict__ Aq, const f16* __restrict__ Bk,
                     float* __restrict__ C, const float* __restrict__ temp,
                     int rowOff)
{
  __shared__ __align__(16) f16 lds[2][2][256 * 64];   // [dbuf][A/B] = 128 KB

  const int t  = threadIdx.x;          // 0..511
  const int l  = t & 63;
  const int w  = t >> 6;               // wave 0..7
  const int wm = w >> 2;               // M half (128 rows)
  const int wn = w & 3;                // N quarter (64 cols)
  const int m0 = blockIdx.y * 256;     // row block
  const int n0 = blockIdx.x * 256;     // column block
  const int fr = l & 15;
  const int fg = l >> 4;

  const int srow = w * 8 + (l >> 3);
  const int koff = ((l & 7) ^ (l >> 3)) * 8;   // f16 units, 16B-aligned

  f32x4 acc[8][4];
#pragma unroll
  for (int m = 0; m < 8; ++m)
#pragma unroll
    for (int n = 0; n < 4; ++n) acc[m][n] = (f32x4){0.f, 0.f, 0.f, 0.f};

  auto stage = [&](int d, int kt) {
    const int kb = kt * 64 + koff;
#pragma unroll
    for (int j = 0; j < 4; ++j)
      gl_lds16(Aq + (size_t)(m0 + j * 64 + srow) * 768 + kb,
               &lds[d][0][j * 4096 + w * 512]);
#pragma unroll
    for (int j = 0; j < 4; ++j)
      gl_lds16(Bk + (size_t)(n0 + j * 64 + srow) * 768 + kb,
               &lds[d][1][j * 4096 + w * 512]);
  };

  stage(0, 0);

#pragma unroll 1
  for (int kt = 0; kt < 12; ++kt) {
    const int d = kt & 1;
    if (kt + 1 < 12) {
      stage(d ^ 1, kt + 1);
      asm volatile("s_waitcnt vmcnt(8)" ::: "memory");
    } else {
      asm volatile("s_waitcnt vmcnt(0)" ::: "memory");
    }
    __builtin_amdgcn_s_barrier();
    __builtin_amdgcn_sched_barrier(0);

    const f16* Ab = &lds[d][0][0];
    const f16* Bb = &lds[d][1][0];
#pragma unroll
    for (int kk = 0; kk < 2; ++kk) {
      const int g = ((kk * 4 + fg) ^ (fr & 7)) * 8;
      f16x8 bf[4];
#pragma unroll
      for (int n = 0; n < 4; ++n)
        bf[n] = *(const f16x8*)&Bb[(wn * 64 + n * 16 + fr) * 64 + g];
#pragma unroll
      for (int mh = 0; mh < 2; ++mh) {
        f16x8 af[4];
#pragma unroll
        for (int i = 0; i < 4; ++i)
          af[i] = *(const f16x8*)&Ab[(wm * 128 + (mh * 4 + i) * 16 + fr) * 64 + g];
        __builtin_amdgcn_s_setprio(1);
#pragma unroll
        for (int i = 0; i < 4; ++i)
#pragma unroll
          for (int n = 0; n < 4; ++n)
            acc[mh * 4 + i][n] = __builtin_amdgcn_mfma_f32_16x16x32_f16(
                af[i], bf[n], acc[mh * 4 + i][n], 0, 0, 0);
        __builtin_amdgcn_s_setprio(0);
      }
    }
    __builtin_amdgcn_sched_barrier(0);
    __builtin_amdgcn_s_barrier();
  }

  const float invts = 1.0f / (temp[0] * 16.0f);
#pragma unroll
  for (int m = 0; m < 8; ++m)
#pragma unroll
    for (int n = 0; n < 4; ++n) {
      const int gcol = n0 + wn * 64 + n * 16 + fr;
#pragma unroll
      for (int j = 0; j < 4; ++j) {
        const int lrow = m0 + wm * 128 + m * 16 + fg * 4 + j;
        float x = acc[m][n][j] * invts;
        if (rowOff + lrow == gcol) x = NEGVAL;
        C[(size_t)lrow * NN + gcol] = x;
      }
    }
}

// ---------------------------------------------------------------------------
// topk_softmax v5: v4 (proven R14) + fused sparse-AV tail. After computing
// normalized weights pb[i]*inv and indices jb[i] in LDS, thread t directly
// accumulates out[grow][t] = sum_i (pb[i]*inv) * V[jb[i]*DD + t] — identical
// order and f32 rounding as the old sparse_av kernel -> bit-identical output.
// Eliminates the sparse_av dispatch and the wts/idx memory round-trip.
// ---------------------------------------------------------------------------
__global__ __launch_bounds__(256)
void topk_softmax5(const float* __restrict__ Sc, int rowOff,
                   const float* __restrict__ V, float* __restrict__ out)
{
  __shared__ unsigned hist[256];
  __shared__ float    candv[CCAP];
  __shared__ int      candi[CCAP];
  __shared__ float    pb[CAP];
  __shared__ int      jb[CAP];
  __shared__ float    wmax[4], wsum[4];
  __shared__ int      wtot[4];
  __shared__ int      sB;
  __shared__ unsigned uT;

  const int t = threadIdx.x;
  const int l = t & 63;
  const int w = t >> 6;
  const int grow = rowOff + blockIdx.x;
  const float* srow = Sc + (size_t)blockIdx.x * NN;

  float v[32];
#pragma unroll
  for (int c = 0; c < 8; ++c) {
    float4 f = *(const float4*)(srow + ((size_t)c * 256 + t) * 4);
    v[c * 4 + 0] = f.x; v[c * 4 + 1] = f.y; v[c * 4 + 2] = f.z; v[c * 4 + 3] = f.w;
  }

  float lm = -3.0e38f;
#pragma unroll
  for (int r = 0; r < 32; ++r) lm = fmaxf(lm, v[r]);
#pragma unroll
  for (int off = 32; off; off >>= 1) lm = fmaxf(lm, __shfl_xor(lm, off));
  if (l == 0) wmax[w] = lm;
  __syncthreads();
  const float m = fmaxf(fmaxf(wmax[0], wmax[1]), fmaxf(wmax[2], wmax[3]));

  float lo = m - 2.5f;
  float invw = 0.0f;
  int B = -1;
  for (int iter = 0; iter < 8; ++iter) {
    hist[t] = 0u;
    __syncthreads();
    invw = 256.0f / (m - lo);
#pragma unroll
    for (int r = 0; r < 32; ++r) {
      float s = v[r];
      if (s >= lo) {
        int b = (int)((s - lo) * invw);
        b = (b > 255) ? 255 : b;
        atomicAdd(&hist[b], 1u);
      }
    }
    __syncthreads();
    const int c = (int)hist[t];
    int x = c;
#pragma unroll
    for (int off = 1; off < 64; off <<= 1) {
      int y = __shfl_down(x, off);
      if (l + off < 64) x += y;
    }
    if (l == 0) wtot[w] = x;
    __syncthreads();
    int hi = 0;
#pragma unroll
    for (int ww = 0; ww < 4; ++ww) if (ww > w) hi += wtot[ww];
    const int S = x + hi;
    const int total = wtot[0] + wtot[1] + wtot[2] + wtot[3];
    if (total >= TOPK) {
      if (S >= TOPK && S - c < TOPK) sB = t;
      __syncthreads();
      B = sB;
      break;
    }
    __syncthreads();
    lo = m - 2.5f * (float)(2 << iter);
  }
  if (B < 0) B = 0;

  int cc = 0;
#pragma unroll
  for (int r = 0; r < 32; ++r) {
    float s = v[r];
    if (s >= lo) {
      int b = (int)((s - lo) * invw);
      b = (b > 255) ? 255 : b;
      if (b >= B) ++cc;
    }
  }
  int x = cc;
#pragma unroll
  for (int off = 1; off < 64; off <<= 1) {
    int y = __shfl_up(x, off);
    if (l >= off) x += y;
  }
  if (l == 63) wtot[w] = x;
  __syncthreads();
  int lowsum = 0;
#pragma unroll
  for (int ww = 0; ww < 4; ++ww) if (ww < w) lowsum += wtot[ww];
  int base = lowsum + x - cc;
  const int ctotal = wtot[0] + wtot[1] + wtot[2] + wtot[3];
#pragma unroll
  for (int r = 0; r < 32; ++r) {
    float s = v[r];
    if (s >= lo) {
      int b = (int)((s - lo) * invw);
      b = (b > 255) ? 255 : b;
      if (b >= B) {
        if (base < CCAP) {
          candv[base] = s;
          candi[base] = ((r >> 2) * 256 + t) * 4 + (r & 3);
        }
        ++base;
      }
    }
  }
  __syncthreads();
  const int L = (ctotal < CCAP) ? ctotal : CCAP;

  if (t == 0) uT = 0xFFFFFFFFu;
  __syncthreads();
  if (t < L) {
    float vi = candv[t];
    int g = 0;
    for (int j = 0; j < L; ++j) g += (candv[j] > vi) ? 1 : 0;
    if (g <= TOPK - 1) {
      unsigned ub = __float_as_uint(vi);
      unsigned u = (ub & 0x80000000u) ? ~ub : (ub | 0x80000000u);
      atomicMin(&uT, u);
    }
  }
  __syncthreads();
  const unsigned uth = uT;
  const float T = __uint_as_float((uth & 0x80000000u) ? (uth & 0x7FFFFFFFu) : ~uth);

  const bool keep = (t < L) && (candv[t] >= T);
  const unsigned long long bal = __ballot(keep);
  if (l == 0) wtot[w] = __popcll(bal);
  __syncthreads();
  int lowsum2 = 0;
#pragma unroll
  for (int ww = 0; ww < 4; ++ww) if (ww < w) lowsum2 += wtot[ww];
  const int pos = lowsum2 + __popcll(bal & ((1ULL << l) - 1ULL));
  const int total2 = wtot[0] + wtot[1] + wtot[2] + wtot[3];
  if (keep && pos < CAP) {
    pb[pos] = __expf(candv[t] - m);
    jb[pos] = candi[t];
  }
  __syncthreads();
  const int L2 = (total2 < CAP) ? total2 : CAP;

  float ps = 0.0f;
  for (int i = t; i < L2; i += 256) ps += pb[i];
#pragma unroll
  for (int off = 32; off; off >>= 1) ps += __shfl_xor(ps, off);
  if (l == 0) wsum[w] = ps;
  __syncthreads();
  const float inv = 1.0f / (wsum[0] + wsum[1] + wsum[2] + wsum[3]);

  // ---- fused sparse AV (was sparse_av kernel): thread t owns out col t ----
  float acc = 0.0f;
  for (int i = 0; i < L2; ++i)
    acc = fmaf(pb[i] * inv, V[(size_t)jb[i] * DD + t], acc);
  out[(size_t)grow * DD + t] = acc;
}

// ---------------------------------------------------------------------------
extern "C" void kernel_launch(void* const* d_in, const int* in_sizes, int n_in,
                              void* d_out, int out_size, void* d_ws, size_t ws_size,
                              hipStream_t stream)
{
  const float* X    = (const float*)d_in[0];
  const float* Wq   = (const float*)d_in[1];
  const float* bq   = (const float*)d_in[2];
  const float* Wk   = (const float*)d_in[3];
  const float* bk   = (const float*)d_in[4];
  const float* Wv   = (const float*)d_in[5];
  const float* bv   = (const float*)d_in[6];
  const float* temp = (const float*)d_in[7];
  float* out = (float*)d_out;
  float* ws  = (float*)d_ws;

  const size_t avail = ws_size / sizeof(float);

  const size_t szV   = (size_t)NN * DD;          // V f32
  const size_t szHL  = (size_t)NN * 768 / 2;     // f16 hi/lo buf (float units)
  const size_t fixed = szV + 2 * szHL;

  size_t o = 0;
  float* Vbuf = ws + o; o += szV;
  f16*   Qs   = (f16*)(ws + o); o += szHL;
  f16*   Ks   = (f16*)(ws + o); o += szHL;

  if (avail <= fixed + (size_t)256 * NN) return;
  int CR = (int)(((avail - fixed) / NN) / 256) * 256;
  if (CR > CRMAX) CR = CRMAX;       // 64 MB chunk: write->read->overwrite
  if (CR > NN) CR = NN;             // cycle stays L3-resident
  float* Sc = ws + o;

  dim3 blk(256);
  dim3 blk2(512);

  // fused Q/K/V projections (exact f32 math; shared-X 64x64x3, BK=32)
  gemm_qkv<<<dim3(NN/64, 4), blk, 0, stream>>>(X, Wq, bq, Wk, bk, Wv, bv,
                                               Qs, Ks, Vbuf);

  for (int r0 = 0; r0 < NN; r0 += CR) {
    const int rows = (NN - r0 < CR) ? (NN - r0) : CR;
    // grid axes swapped: x = column blocks (32), y = row blocks (rows/256)
    gemm_scores_f16<<<dim3(NN/256, rows/256), blk2, 0, stream>>>(
        Qs + (size_t)r0 * 768, Ks, Sc, temp, r0);
    // fused top-k + softmax + sparse AV (writes out directly)
    topk_softmax5<<<dim3(rows), blk, 0, stream>>>(Sc, r0, Vbuf, out);
  }
}

// Round 20
// 312.445 us; speedup vs baseline: 1.0148x; 1.0148x over previous
//
#include <hip/hip_runtime.h>
#include <math.h>

#define NN 8192
#define DD 256
#define TOPK 64
#define CAP 96            // survivor capacity per row
#define CCAP 256          // candidate capacity for exact select
#define CRMAX 2048        // score-chunk rows: Sc = 64 MB -> L3-resident
#define NEGVAL (-1000000000.0f)

typedef _Float16 f16;
typedef f16  f16x4 __attribute__((ext_vector_type(4)));
typedef f16  f16x8 __attribute__((ext_vector_type(8)));
typedef float f32x4 __attribute__((ext_vector_type(4)));

// ---------------------------------------------------------------------------
// Fused QKV projection (R11/R13, proven 55us): shared-X 64x64x3 tiles, BK=32,
// padded LDS rows (stride 68). Per-output fmaf chain is k-ascending ->
// bitwise-identical Q/K/V (selection boundary demands exactness).
// Q,K written directly as f16 hi/lo score layout; V as f32.
// ---------------------------------------------------------------------------
__global__ __launch_bounds__(256)
void gemm_qkv(const float* __restrict__ X,
              const float* __restrict__ Wq, const float* __restrict__ bq,
              const float* __restrict__ Wk, const float* __restrict__ bk,
              const float* __restrict__ Wv, const float* __restrict__ bv,
              f16* __restrict__ Qs, f16* __restrict__ Ks,
              float* __restrict__ Vf)
{
  __shared__ float As[32][68];
  __shared__ float Bs[3][32][68];
  const int t  = threadIdx.x;
  const int tm = t & 15;
  const int tn = t >> 4;
  const int m0 = blockIdx.x * 64;
  const int n0 = blockIdx.y * 64;

  float acc[3][4][4];
#pragma unroll
  for (int g = 0; g < 3; ++g)
#pragma unroll
    for (int i = 0; i < 4; ++i)
#pragma unroll
      for (int j = 0; j < 4; ++j) acc[g][i][j] = 0.0f;

  for (int k0 = 0; k0 < DD; k0 += 32) {
    __syncthreads();
#pragma unroll
    for (int i = 0; i < 2; ++i) {
      const int slot = t + i * 256;
      const int row  = slot >> 3;
      const int c4   = (slot & 7) << 2;
      float4 av = *(const float4*)(X + (size_t)(m0 + row) * DD + k0 + c4);
      As[c4 + 0][row] = av.x; As[c4 + 1][row] = av.y;
      As[c4 + 2][row] = av.z; As[c4 + 3][row] = av.w;
      float4 q4 = *(const float4*)(Wq + (size_t)(n0 + row) * DD + k0 + c4);
      Bs[0][c4 + 0][row] = q4.x; Bs[0][c4 + 1][row] = q4.y;
      Bs[0][c4 + 2][row] = q4.z; Bs[0][c4 + 3][row] = q4.w;
      float4 k4 = *(const float4*)(Wk + (size_t)(n0 + row) * DD + k0 + c4);
      Bs[1][c4 + 0][row] = k4.x; Bs[1][c4 + 1][row] = k4.y;
      Bs[1][c4 + 2][row] = k4.z; Bs[1][c4 + 3][row] = k4.w;
      float4 v4 = *(const float4*)(Wv + (size_t)(n0 + row) * DD + k0 + c4);
      Bs[2][c4 + 0][row] = v4.x; Bs[2][c4 + 1][row] = v4.y;
      Bs[2][c4 + 2][row] = v4.z; Bs[2][c4 + 3][row] = v4.w;
    }
    __syncthreads();
#pragma unroll
    for (int kk = 0; kk < 32; ++kk) {
      float a[4];
      *(float4*)&a[0] = *(const float4*)&As[kk][tm * 4];
      float b0[4], b1[4], b2[4];
      *(float4*)&b0[0] = *(const float4*)&Bs[0][kk][tn * 4];
      *(float4*)&b1[0] = *(const float4*)&Bs[1][kk][tn * 4];
      *(float4*)&b2[0] = *(const float4*)&Bs[2][kk][tn * 4];
#pragma unroll
      for (int i = 0; i < 4; ++i)
#pragma unroll
        for (int j = 0; j < 4; ++j) {
          acc[0][i][j] = fmaf(a[i], b0[j], acc[0][i][j]);
          acc[1][i][j] = fmaf(a[i], b1[j], acc[1][i][j]);
          acc[2][i][j] = fmaf(a[i], b2[j], acc[2][i][j]);
        }
    }
  }

#pragma unroll
  for (int r = 0; r < 4; ++r) {
    const int grow  = m0 + tm * 4 + r;
    const int gcol0 = n0 + tn * 4;
    {
      f16x4 h4, l4;
#pragma unroll
      for (int c = 0; c < 4; ++c) {
        const float val = acc[0][r][c] + bq[gcol0 + c];
        f16 h = (f16)val;
        h4[c] = h;
        l4[c] = (f16)(val - (float)h);
      }
      f16* base = Qs + (size_t)grow * 768 + gcol0;
      *(f16x4*)(base)       = h4;
      *(f16x4*)(base + 256) = h4;
      *(f16x4*)(base + 512) = l4;
    }
    {
      f16x4 h4, l4;
#pragma unroll
      for (int c = 0; c < 4; ++c) {
        const float val = acc[1][r][c] + bk[gcol0 + c];
        f16 h = (f16)val;
        h4[c] = h;
        l4[c] = (f16)(val - (float)h);
      }
      f16* base = Ks + (size_t)grow * 768 + gcol0;
      *(f16x4*)(base)       = h4;
      *(f16x4*)(base + 256) = l4;
      *(f16x4*)(base + 512) = h4;
    }
    {
      float val[4];
#pragma unroll
      for (int c = 0; c < 4; ++c)
        val[c] = acc[2][r][c] + bv[gcol0 + c];
      *(float4*)(Vf + (size_t)grow * DD + gcol0) =
          make_float4(val[0], val[1], val[2], val[3]);
    }
  }
}

// ---------------------------------------------------------------------------
typedef __attribute__((address_space(1))) const void GV;
typedef __attribute__((address_space(3))) void LV;
__device__ __forceinline__ void gl_lds16(const void* g, void* l) {
  __builtin_amdgcn_global_load_lds((GV*)g, (LV*)l, 16, 0, 0);
}

// ---------------------------------------------------------------------------
// MFMA scores GEMM v4b (R18, proven): 256x256 tile, BK=64, 8 waves, 2 LDS
// dbufs, counted-vmcnt depth-1 pipeline, both-sides swizzle; grid axes
// swapped (x = column block) for per-XCD L2 locality of the K panels.
// ---------------------------------------------------------------------------
__global__ __launch_bounds__(512, 1)
void gemm_scores_f16(const f16* __restrict__ Aq, const f16* __restrict__ Bk,
                     float* __restrict__ C, const float* __restrict__ temp,
                     int rowOff)
{
  __shared__ __align__(16) f16 lds[2][2][256 * 64];   // [dbuf][A/B] = 128 KB

  const int t  = threadIdx.x;          // 0..511
  const int l  = t & 63;
  const int w  = t >> 6;               // wave 0..7
  const int wm = w >> 2;               // M half (128 rows)
  const int wn = w & 3;                // N quarter (64 cols)
  const int m0 = blockIdx.y * 256;     // row block
  const int n0 = blockIdx.x * 256;     // column block
  const int fr = l & 15;
  const int fg = l >> 4;

  const int srow = w * 8 + (l >> 3);
  const int koff = ((l & 7) ^ (l >> 3)) * 8;   // f16 units, 16B-aligned

  f32x4 acc[8][4];
#pragma unroll
  for (int m = 0; m < 8; ++m)
#pragma unroll
    for (int n = 0; n < 4; ++n) acc[m][n] = (f32x4){0.f, 0.f, 0.f, 0.f};

  auto stage = [&](int d, int kt) {
    const int kb = kt * 64 + koff;
#pragma unroll
    for (int j = 0; j < 4; ++j)
      gl_lds16(Aq + (size_t)(m0 + j * 64 + srow) * 768 + kb,
               &lds[d][0][j * 4096 + w * 512]);
#pragma unroll
    for (int j = 0; j < 4; ++j)
      gl_lds16(Bk + (size_t)(n0 + j * 64 + srow) * 768 + kb,
               &lds[d][1][j * 4096 + w * 512]);
  };

  stage(0, 0);

#pragma unroll 1
  for (int kt = 0; kt < 12; ++kt) {
    const int d = kt & 1;
    if (kt + 1 < 12) {
      stage(d ^ 1, kt + 1);
      asm volatile("s_waitcnt vmcnt(8)" ::: "memory");
    } else {
      asm volatile("s_waitcnt vmcnt(0)" ::: "memory");
    }
    __builtin_amdgcn_s_barrier();
    __builtin_amdgcn_sched_barrier(0);

    const f16* Ab = &lds[d][0][0];
    const f16* Bb = &lds[d][1][0];
#pragma unroll
    for (int kk = 0; kk < 2; ++kk) {
      const int g = ((kk * 4 + fg) ^ (fr & 7)) * 8;
      f16x8 bf[4];
#pragma unroll
      for (int n = 0; n < 4; ++n)
        bf[n] = *(const f16x8*)&Bb[(wn * 64 + n * 16 + fr) * 64 + g];
#pragma unroll
      for (int mh = 0; mh < 2; ++mh) {
        f16x8 af[4];
#pragma unroll
        for (int i = 0; i < 4; ++i)
          af[i] = *(const f16x8*)&Ab[(wm * 128 + (mh * 4 + i) * 16 + fr) * 64 + g];
        __builtin_amdgcn_s_setprio(1);
#pragma unroll
        for (int i = 0; i < 4; ++i)
#pragma unroll
          for (int n = 0; n < 4; ++n)
            acc[mh * 4 + i][n] = __builtin_amdgcn_mfma_f32_16x16x32_f16(
                af[i], bf[n], acc[mh * 4 + i][n], 0, 0, 0);
        __builtin_amdgcn_s_setprio(0);
      }
    }
    __builtin_amdgcn_sched_barrier(0);
    __builtin_amdgcn_s_barrier();
  }

  const float invts = 1.0f / (temp[0] * 16.0f);
#pragma unroll
  for (int m = 0; m < 8; ++m)
#pragma unroll
    for (int n = 0; n < 4; ++n) {
      const int gcol = n0 + wn * 64 + n * 16 + fr;
#pragma unroll
      for (int j = 0; j < 4; ++j) {
        const int lrow = m0 + wm * 128 + m * 16 + fg * 4 + j;
        float x = acc[m][n][j] * invts;
        if (rowOff + lrow == gcol) x = NEGVAL;
        C[(size_t)lrow * NN + gcol] = x;
      }
    }
}

// ---------------------------------------------------------------------------
// topk_softmax v4 (proven R14): candidate buffer stores values+indices;
// final survivor pass on the <=256 candidates.
// ---------------------------------------------------------------------------
__global__ __launch_bounds__(256)
void topk_softmax4(const float* __restrict__ Sc, int rowOff,
                   float* __restrict__ wts, int* __restrict__ idx,
                   int* __restrict__ cnt)
{
  __shared__ unsigned hist[256];
  __shared__ float    candv[CCAP];
  __shared__ int      candi[CCAP];
  __shared__ float    pb[CAP];
  __shared__ int      jb[CAP];
  __shared__ float    wmax[4], wsum[4];
  __shared__ int      wtot[4];
  __shared__ int      sB;
  __shared__ unsigned uT;

  const int t = threadIdx.x;
  const int l = t & 63;
  const int w = t >> 6;
  const int grow = rowOff + blockIdx.x;
  const float* srow = Sc + (size_t)blockIdx.x * NN;

  float v[32];
#pragma unroll
  for (int c = 0; c < 8; ++c) {
    float4 f = *(const float4*)(srow + ((size_t)c * 256 + t) * 4);
    v[c * 4 + 0] = f.x; v[c * 4 + 1] = f.y; v[c * 4 + 2] = f.z; v[c * 4 + 3] = f.w;
  }

  float lm = -3.0e38f;
#pragma unroll
  for (int r = 0; r < 32; ++r) lm = fmaxf(lm, v[r]);
#pragma unroll
  for (int off = 32; off; off >>= 1) lm = fmaxf(lm, __shfl_xor(lm, off));
  if (l == 0) wmax[w] = lm;
  __syncthreads();
  const float m = fmaxf(fmaxf(wmax[0], wmax[1]), fmaxf(wmax[2], wmax[3]));

  float lo = m - 2.5f;
  float invw = 0.0f;
  int B = -1;
  for (int iter = 0; iter < 8; ++iter) {
    hist[t] = 0u;
    __syncthreads();
    invw = 256.0f / (m - lo);
#pragma unroll
    for (int r = 0; r < 32; ++r) {
      float s = v[r];
      if (s >= lo) {
        int b = (int)((s - lo) * invw);
        b = (b > 255) ? 255 : b;
        atomicAdd(&hist[b], 1u);
      }
    }
    __syncthreads();
    const int c = (int)hist[t];
    int x = c;
#pragma unroll
    for (int off = 1; off < 64; off <<= 1) {
      int y = __shfl_down(x, off);
      if (l + off < 64) x += y;
    }
    if (l == 0) wtot[w] = x;
    __syncthreads();
    int hi = 0;
#pragma unroll
    for (int ww = 0; ww < 4; ++ww) if (ww > w) hi += wtot[ww];
    const int S = x + hi;
    const int total = wtot[0] + wtot[1] + wtot[2] + wtot[3];
    if (total >= TOPK) {
      if (S >= TOPK && S - c < TOPK) sB = t;
      __syncthreads();
      B = sB;
      break;
    }
    __syncthreads();
    lo = m - 2.5f * (float)(2 << iter);
  }
  if (B < 0) B = 0;

  int cc = 0;
#pragma unroll
  for (int r = 0; r < 32; ++r) {
    float s = v[r];
    if (s >= lo) {
      int b = (int)((s - lo) * invw);
      b = (b > 255) ? 255 : b;
      if (b >= B) ++cc;
    }
  }
  int x = cc;
#pragma unroll
  for (int off = 1; off < 64; off <<= 1) {
    int y = __shfl_up(x, off);
    if (l >= off) x += y;
  }
  if (l == 63) wtot[w] = x;
  __syncthreads();
  int lowsum = 0;
#pragma unroll
  for (int ww = 0; ww < 4; ++ww) if (ww < w) lowsum += wtot[ww];
  int base = lowsum + x - cc;
  const int ctotal = wtot[0] + wtot[1] + wtot[2] + wtot[3];
#pragma unroll
  for (int r = 0; r < 32; ++r) {
    float s = v[r];
    if (s >= lo) {
      int b = (int)((s - lo) * invw);
      b = (b > 255) ? 255 : b;
      if (b >= B) {
        if (base < CCAP) {
          candv[base] = s;
          candi[base] = ((r >> 2) * 256 + t) * 4 + (r & 3);
        }
        ++base;
      }
    }
  }
  __syncthreads();
  const int L = (ctotal < CCAP) ? ctotal : CCAP;

  if (t == 0) uT = 0xFFFFFFFFu;
  __syncthreads();
  if (t < L) {
    float vi = candv[t];
    int g = 0;
    for (int j = 0; j < L; ++j) g += (candv[j] > vi) ? 1 : 0;
    if (g <= TOPK - 1) {
      unsigned ub = __float_as_uint(vi);
      unsigned u = (ub & 0x80000000u) ? ~ub : (ub | 0x80000000u);
      atomicMin(&uT, u);
    }
  }
  __syncthreads();
  const unsigned uth = uT;
  const float T = __uint_as_float((uth & 0x80000000u) ? (uth & 0x7FFFFFFFu) : ~uth);

  const bool keep = (t < L) && (candv[t] >= T);
  const unsigned long long bal = __ballot(keep);
  if (l == 0) wtot[w] = __popcll(bal);
  __syncthreads();
  int lowsum2 = 0;
#pragma unroll
  for (int ww = 0; ww < 4; ++ww) if (ww < w) lowsum2 += wtot[ww];
  const int pos = lowsum2 + __popcll(bal & ((1ULL << l) - 1ULL));
  const int total2 = wtot[0] + wtot[1] + wtot[2] + wtot[3];
  if (keep && pos < CAP) {
    pb[pos] = __expf(candv[t] - m);
    jb[pos] = candi[t];
  }
  __syncthreads();
  const int L2 = (total2 < CAP) ? total2 : CAP;

  float ps = 0.0f;
  for (int i = t; i < L2; i += 256) ps += pb[i];
#pragma unroll
  for (int off = 32; off; off >>= 1) ps += __shfl_xor(ps, off);
  if (l == 0) wsum[w] = ps;
  __syncthreads();
  const float inv = 1.0f / (wsum[0] + wsum[1] + wsum[2] + wsum[3]);
  for (int i = t; i < L2; i += 256) {
    wts[(size_t)grow * CAP + i] = pb[i] * inv;
    idx[(size_t)grow * CAP + i] = jb[i];
  }
  if (t == 0) cnt[grow] = L2;
}

// ---------------------------------------------------------------------------
__global__ __launch_bounds__(256)
void sparse_av(const float* __restrict__ V, const float* __restrict__ wts,
               const int* __restrict__ idx, const int* __restrict__ cnt,
               float* __restrict__ out)
{
  __shared__ float wl[CAP];
  __shared__ int   jl[CAP];
  const int t = threadIdx.x;
  const int row = blockIdx.x;
  const int L = cnt[row];
  if (t < CAP && t < L) {
    wl[t] = wts[(size_t)row * CAP + t];
    jl[t] = idx[(size_t)row * CAP + t];
  }
  __syncthreads();
  float acc = 0.0f;
  for (int i = 0; i < L; ++i)
    acc = fmaf(wl[i], V[(size_t)jl[i] * DD + t], acc);
  out[(size_t)row * DD + t] = acc;
}

// ---------------------------------------------------------------------------
extern "C" void kernel_launch(void* const* d_in, const int* in_sizes, int n_in,
                              void* d_out, int out_size, void* d_ws, size_t ws_size,
                              hipStream_t stream)
{
  const float* X    = (const float*)d_in[0];
  const float* Wq   = (const float*)d_in[1];
  const float* bq   = (const float*)d_in[2];
  const float* Wk   = (const float*)d_in[3];
  const float* bk   = (const float*)d_in[4];
  const float* Wv   = (const float*)d_in[5];
  const float* bv   = (const float*)d_in[6];
  const float* temp = (const float*)d_in[7];
  float* out = (float*)d_out;
  float* ws  = (float*)d_ws;

  const size_t avail = ws_size / sizeof(float);

  const size_t szV   = (size_t)NN * DD;          // V f32
  const size_t szHL  = (size_t)NN * 768 / 2;     // f16 hi/lo buf (float units)
  const size_t szWts = (size_t)NN * CAP;
  const size_t szIdx = (size_t)NN * CAP;
  const size_t szCnt = NN;
  const size_t fixed = szV + 2 * szHL + szWts + szIdx + szCnt;

  size_t o = 0;
  float* Vbuf = ws + o; o += szV;
  f16*   Qs   = (f16*)(ws + o); o += szHL;
  f16*   Ks   = (f16*)(ws + o); o += szHL;
  float* wts  = ws + o; o += szWts;
  int*   idxb = (int*)(ws + o); o += szIdx;
  int*   cntb = (int*)(ws + o); o += szCnt;

  if (avail <= fixed + (size_t)256 * NN) return;
  int CR = (int)(((avail - fixed) / NN) / 256) * 256;
  if (CR > CRMAX) CR = CRMAX;       // 64 MB chunk: write->read->overwrite
  if (CR > NN) CR = NN;             // cycle stays L3-resident
  float* Sc = ws + o;

  dim3 blk(256);
  dim3 blk2(512);

  // fused Q/K/V projections (exact f32 math; shared-X 64x64x3, BK=32)
  gemm_qkv<<<dim3(NN/64, 4), blk, 0, stream>>>(X, Wq, bq, Wk, bk, Wv, bv,
                                               Qs, Ks, Vbuf);

  for (int r0 = 0; r0 < NN; r0 += CR) {
    const int rows = (NN - r0 < CR) ? (NN - r0) : CR;
    // grid axes swapped: x = column blocks (32), y = row blocks (rows/256)
    gemm_scores_f16<<<dim3(NN/256, rows/256), blk2, 0, stream>>>(
        Qs + (size_t)r0 * 768, Ks, Sc, temp, r0);
    topk_softmax4<<<dim3(rows), blk, 0, stream>>>(Sc, r0, wts, idxb, cntb);
  }

  sparse_av<<<dim3(NN), blk, 0, stream>>>(Vbuf, wts, idxb, cntb, out);
}